// Round 6
// baseline (3881.802 us; speedup 1.0000x reference)
//
#include <hip/hip_runtime.h>

#define BT 32768
#define CDIM 512
#define KCB 1024
#define NQ 4
#define IDX_BASE (BT*CDIM)
#define LOSS_OFF (BT*CDIM + BT*NQ)
#define CAND_MAX 64

// ws byte offsets
#define WS_LIST   256
#define WS_A2     (WS_LIST + BT*4)
#define WS_B2     (WS_A2 + BT*4)
#define WS_RBC    (WS_B2 + NQ*KCB*4)
#define WS_CBB    (WS_RBC + BT*CDIM*2)
#define WS_CCNT   (WS_CBB + NQ*KCB*CDIM*2)
#define WS_CANDK  (WS_CCNT + BT*4)
#define WS_CANDS  (WS_CANDK + BT*CAND_MAX*4)

typedef __attribute__((ext_vector_type(8))) short bf16x8;
typedef __attribute__((ext_vector_type(4))) float f32x4;

__device__ __forceinline__ unsigned int f2bf(float f) {
  unsigned int u = __float_as_uint(f);
  return (u + 0x7fffu + ((u >> 16) & 1u)) >> 16;  // RNE
}

// mask storage formats: 0=u8, 1=i32, 2=i64, 3=bf16, 4=f32
__device__ __forceinline__ int mask_at(const void* m, int t, int flag) {
  switch (flag) {
    case 0:  return ((const unsigned char*)m)[t] != 0;
    case 1:  return ((const int*)m)[t] != 0;
    case 2:  return ((const unsigned long long*)m)[t] != 0ull;
    case 3:  return ((const unsigned short*)m)[t] != 0;
    default: return ((const float*)m)[t] != 0.0f;
  }
}

// Detect mask format, count n_valid, build order-preserving compacted list.
__global__ void k_prep(const unsigned char* mask, int* wsi, float* wsf, int* list) {
  __shared__ int s_not01, s_off1, s_offn0, s_odd, s_fm;
  __shared__ int s_cnt[1024];
  int tid = threadIdx.x;
  if (tid == 0) { s_not01 = 0; s_off1 = 0; s_offn0 = 0; s_odd = 0; }
  __syncthreads();
  int l_not01 = 0, l_off1 = 0, l_offn0 = 0, l_odd = 0;
  for (int o = tid; o < BT; o += 1024) {
    unsigned char b = mask[o];
    if (b) {
      if (b > 1) l_not01 = 1;
      int m4 = o & 3;
      if (m4 == 1) l_off1 = 1;
      if (m4) l_offn0 = 1;
      if ((o & 7) >= 4) l_odd = 1;
    }
  }
  if (l_not01) atomicOr(&s_not01, 1);
  if (l_off1)  atomicOr(&s_off1, 1);
  if (l_offn0) atomicOr(&s_offn0, 1);
  if (l_odd)   atomicOr(&s_odd, 1);
  __syncthreads();
  if (tid == 0) {
    int fm;
    if (s_not01)      fm = s_off1 ? 3 : 4;
    else if (s_offn0) fm = 0;
    else if (s_odd)   fm = 1;
    else              fm = 2;
    s_fm = fm; wsi[0] = fm;
    wsf[8] = 0.0f;                       // loss accumulator
    wsf[12] = 0.f; wsf[13] = 0.f; wsf[14] = 0.f; wsf[15] = 0.f;  // b2max
  }
  __syncthreads();
  int fm = s_fm;
  int base = tid * 32, cnt = 0;
  for (int u = 0; u < 32; u++) cnt += mask_at(mask, base + u, fm);
  s_cnt[tid] = cnt;
  __syncthreads();
  if (tid == 0) {
    int run = 0;
    for (int q = 0; q < 1024; q++) { int c = s_cnt[q]; s_cnt[q] = run; run += c; }
    wsi[2] = run;
  }
  __syncthreads();
  int off = s_cnt[tid];
  for (int u = 0; u < 32; u++) {
    int t = base + u;
    if (mask_at(mask, t, fm)) list[off++] = t;
  }
}

// Invalid tokens: x_q row = 0, indices = -1.
__global__ void k_fill(const void* mask, float* out, const int* wsi) {
  int w = threadIdx.x >> 6, lane = threadIdx.x & 63;
  int t = blockIdx.x * 4 + w;
  if (t >= BT) return;
  if (mask_at(mask, t, wsi[0])) return;
  float4 z = make_float4(0.f, 0.f, 0.f, 0.f);
  float4* p = (float4*)(out + (size_t)t * CDIM) + lane * 2;
  p[0] = z; p[1] = z;
  if (lane < NQ) out[IDX_BASE + (size_t)t * NQ + lane] = -1.0f;
}

// b2: exact sequential chain; also per-codebook b2max (atomicMax on positive floats).
__global__ void k_b2(const float* __restrict__ cb, float* __restrict__ b2, float* b2max) {
  __shared__ float st[4][512];
  int w = threadIdx.x >> 6, lane = threadIdx.x & 63;
  int row = blockIdx.x * 4 + w;              // 1024 blocks x 4 rows
  const float4* p = (const float4*)(cb + (size_t)row * CDIM) + lane * 2;
  float4 v0 = p[0], v1 = p[1];
  *(float4*)&st[w][lane * 8] = v0;
  *(float4*)&st[w][lane * 8 + 4] = v1;
  __syncthreads();
  if (threadIdx.x < 4) {
    int r2 = blockIdx.x * 4 + threadIdx.x;
    float s = 0.f;
    for (int c4 = 0; c4 < 128; ++c4) {
      float4 v = *(float4*)&st[threadIdx.x][c4 * 4];
      s = __fadd_rn(s, __fmul_rn(v.x, v.x));
      s = __fadd_rn(s, __fmul_rn(v.y, v.y));
      s = __fadd_rn(s, __fmul_rn(v.z, v.z));
      s = __fadd_rn(s, __fmul_rn(v.w, v.w));
    }
    b2[r2] = s;
    atomicMax((int*)&b2max[r2 >> 10], __float_as_int(s));
  }
}

// cb -> bf16 (RNE), once for all codebooks.
__global__ void k_cvtcb(const float* __restrict__ cb, unsigned short* __restrict__ cbb) {
  size_t i = (size_t)blockIdx.x * blockDim.x + threadIdx.x;   // per 8 elems
  const float4* s = (const float4*)(cb + i * 8);
  float4 a = s[0], b = s[1];
  uint4 u;
  u.x = f2bf(a.x) | (f2bf(a.y) << 16);
  u.y = f2bf(a.z) | (f2bf(a.w) << 16);
  u.z = f2bf(b.x) | (f2bf(b.y) << 16);
  u.w = f2bf(b.z) | (f2bf(b.w) << 16);
  *(uint4*)(cbb + i * 8) = u;
}

// rws[t] = x[t]; rbc[j] = bf16(x[t]); a2c[j] = exact sequential chain; zero candcnt.
__global__ __launch_bounds__(256) void k_init(const float* __restrict__ x,
    float* __restrict__ rws, unsigned short* __restrict__ rbc,
    const int* __restrict__ wsi, const int* __restrict__ list,
    float* __restrict__ a2c, int* __restrict__ candcnt) {
  __shared__ float st[8][512];
  int nv = wsi[2];
  int j0 = blockIdx.x * 8;
  int tid = threadIdx.x;
  if (tid < 8) candcnt[j0 + tid] = 0;
  if (j0 >= nv) return;
  int slot = tid >> 5;
  int j = j0 + slot;
  int c0 = (tid & 31) * 16;
  if (j < nv) {
    int t = list[j];
    const float4* src = (const float4*)(x + (size_t)t * CDIM + c0);
    float4* dst = (float4*)(rws + (size_t)t * CDIM + c0);
    float4 v0 = src[0], v1 = src[1], v2 = src[2], v3 = src[3];
    dst[0] = v0; dst[1] = v1; dst[2] = v2; dst[3] = v3;
    *(float4*)&st[slot][c0]      = v0; *(float4*)&st[slot][c0 + 4]  = v1;
    *(float4*)&st[slot][c0 + 8]  = v2; *(float4*)&st[slot][c0 + 12] = v3;
    uint4 u0, u1;
    u0.x = f2bf(v0.x) | (f2bf(v0.y) << 16); u0.y = f2bf(v0.z) | (f2bf(v0.w) << 16);
    u0.z = f2bf(v1.x) | (f2bf(v1.y) << 16); u0.w = f2bf(v1.z) | (f2bf(v1.w) << 16);
    u1.x = f2bf(v2.x) | (f2bf(v2.y) << 16); u1.y = f2bf(v2.z) | (f2bf(v2.w) << 16);
    u1.z = f2bf(v3.x) | (f2bf(v3.y) << 16); u1.w = f2bf(v3.z) | (f2bf(v3.w) << 16);
    uint4* bd = (uint4*)(rbc + (size_t)j * CDIM + c0);
    bd[0] = u0; bd[1] = u1;
  }
  __syncthreads();
  if (tid < 8) {
    int jj = j0 + tid;
    if (jj < nv) {
      float s = 0.f;
      for (int c4 = 0; c4 < 128; ++c4) {
        float4 v = *(float4*)&st[tid][c4 * 4];
        s = __fadd_rn(s, __fmul_rn(v.x, v.x));
        s = __fadd_rn(s, __fmul_rn(v.y, v.y));
        s = __fadd_rn(s, __fmul_rn(v.z, v.z));
        s = __fadd_rn(s, __fmul_rn(v.w, v.w));
      }
      a2c[jj] = s;
    }
  }
}

// bf16 MFMA GEMM: s_a[j][k] = b2[k] - 2*(rbc_j . cbb_k); per-64k-tile min;
// collect candidates s_a <= tilemin + M into per-token lists.
__global__ __launch_bounds__(256) void k_gemm(const unsigned short* __restrict__ rbc,
    const unsigned short* __restrict__ cbb, const float* __restrict__ b2,
    const float* __restrict__ b2max, const float* __restrict__ a2c,
    const int* __restrict__ wsi, int* __restrict__ candcnt,
    int* __restrict__ candk, float* __restrict__ cands, int ic) {
  __shared__ __align__(16) unsigned short As[128 * 64];
  __shared__ __align__(16) unsigned short Bs[128 * 64];
  int nv = wsi[2];
  int mb = blockIdx.x >> 3, nb = blockIdx.x & 7;
  int m0 = mb * 128;
  if (m0 >= nv) return;
  int tid = threadIdx.x;
  int w = tid >> 6, lane = tid & 63;
  int wm = w >> 1, wn = w & 1;
  f32x4 acc[4][4];
#pragma unroll
  for (int a = 0; a < 4; a++)
#pragma unroll
    for (int b = 0; b < 4; b++) acc[a][b] = (f32x4){0.f, 0.f, 0.f, 0.f};

  const unsigned short* Ag = rbc + (size_t)m0 * CDIM;
  const unsigned short* Bg = cbb + (size_t)(ic * KCB + nb * 128) * CDIM;
  int kq = tid & 7, rb = tid >> 3;
  int l15 = lane & 15, l4 = lane >> 4;

  for (int kc = 0; kc < 8; ++kc) {
    __syncthreads();
#pragma unroll
    for (int s = 0; s < 4; ++s) {
      int row = rb + s * 32;
      int sw = (kq ^ (row & 7)) << 3;
      uint4 av = *(const uint4*)(Ag + (size_t)row * CDIM + kc * 64 + kq * 8);
      *(uint4*)&As[row * 64 + sw] = av;
      uint4 bv = *(const uint4*)(Bg + (size_t)row * CDIM + kc * 64 + kq * 8);
      *(uint4*)&Bs[row * 64 + sw] = bv;
    }
    __syncthreads();
#pragma unroll
    for (int h = 0; h < 2; ++h) {
      bf16x8 af[4], bf[4];
#pragma unroll
      for (int mf = 0; mf < 4; ++mf) {
        int row = wm * 64 + mf * 16 + l15;
        af[mf] = *(const bf16x8*)&As[row * 64 + (((h * 4 + l4) ^ (row & 7)) << 3)];
      }
#pragma unroll
      for (int nf = 0; nf < 4; ++nf) {
        int row = wn * 64 + nf * 16 + l15;
        bf[nf] = *(const bf16x8*)&Bs[row * 64 + (((h * 4 + l4) ^ (row & 7)) << 3)];
      }
#pragma unroll
      for (int mf = 0; mf < 4; ++mf)
#pragma unroll
        for (int nf = 0; nf < 4; ++nf)
          acc[mf][nf] = __builtin_amdgcn_mfma_f32_16x16x32_bf16(af[mf], bf[nf], acc[mf][nf], 0, 0, 0);
    }
  }

  // epilogue: per-row min over this wave's 64 k + candidate collection
  const float* b2p = b2 + ic * KCB;
  float bmax = b2max[ic];
#pragma unroll
  for (int mf = 0; mf < 4; ++mf) {
    float sv[4][4];
    int kg[4];
    float smin[4]; int kmin[4];
#pragma unroll
    for (int q = 0; q < 4; ++q) { smin[q] = __builtin_inff(); kmin[q] = 0; }
#pragma unroll
    for (int nf = 0; nf < 4; ++nf) {
      int k = nb * 128 + wn * 64 + nf * 16 + l15;
      kg[nf] = k;
      float b2k = b2p[k];
#pragma unroll
      for (int q = 0; q < 4; ++q) {
        float s = __fsub_rn(b2k, __fmul_rn(2.0f, acc[mf][nf][q]));
        sv[nf][q] = s;
        if (s < smin[q]) { smin[q] = s; kmin[q] = k; }
      }
    }
#pragma unroll
    for (int d = 1; d < 16; d <<= 1) {
#pragma unroll
      for (int q = 0; q < 4; ++q) {
        float vo = __shfl_xor(smin[q], d, 64);
        int ko = __shfl_xor(kmin[q], d, 64);
        if (vo < smin[q] || (vo == smin[q] && ko < kmin[q])) { smin[q] = vo; kmin[q] = ko; }
      }
    }
#pragma unroll
    for (int q = 0; q < 4; ++q) {
      int j = m0 + wm * 64 + mf * 16 + l4 * 4 + q;
      if (j < nv) {
        float thr = smin[q] + 0.045f * sqrtf(a2c[j] * bmax) + 1e-5f;
#pragma unroll
        for (int nf = 0; nf < 4; ++nf) {
          if (sv[nf][q] <= thr) {
            int pos = atomicAdd(&candcnt[j], 1);
            if (pos < CAND_MAX) {
              candk[(size_t)j * CAND_MAX + pos] = kg[nf];
              cands[(size_t)j * CAND_MAX + pos] = sv[nf][q];
            }
          }
        }
      }
    }
  }
}

// Exact verification + residual update. One wave per token.
__global__ __launch_bounds__(256) void k_pick(const float* __restrict__ x,
    const float* __restrict__ cb, float* rws, unsigned short* __restrict__ rbc,
    const int* __restrict__ list, const int* __restrict__ wsi,
    float* __restrict__ a2c, const float* __restrict__ b2,
    const float* __restrict__ b2max, int* __restrict__ candcnt,
    const int* __restrict__ candk, const float* __restrict__ cands,
    float* __restrict__ out, float* __restrict__ lossacc, int ic) {
  int nv = wsi[2];
  int lane = threadIdx.x & 63;
  int j = blockIdx.x * 4 + (threadIdx.x >> 6);
  if (j >= nv) return;
  int t = __builtin_amdgcn_readfirstlane(list[j]);
  int cnt = candcnt[j];
  if (lane == 0) candcnt[j] = 0;          // reset for next codebook
  float a2v = a2c[j];
  const float* rrow = rws + (size_t)t * CDIM;
  const float* b2p = b2 + ic * KCB;
  const float* cbp = cb + (size_t)ic * KCB * CDIM;
  int kw;
  if (cnt <= CAND_MAX) {
    float sa = __builtin_inff(); int kl = 0;
    if (lane < cnt) {
      sa = cands[(size_t)j * CAND_MAX + lane];
      kl = candk[(size_t)j * CAND_MAX + lane];
    }
    float g = sa;
#pragma unroll
    for (int d = 1; d < 64; d <<= 1) g = fminf(g, __shfl_xor(g, d, 64));
    float M = 0.045f * sqrtf(a2v * b2max[ic]) + 1e-5f;
    bool keep = (lane < cnt) && (sa <= g + M);
    int kk = keep ? kl : 0;
    const float* brow = cbp + (size_t)kk * CDIM;
    float ab = 0.f;
    for (int c4 = 0; c4 < 128; ++c4) {
      float4 rv = ((const float4*)rrow)[c4];
      float4 bv = ((const float4*)brow)[c4];
      ab = __fmaf_rn(rv.x, bv.x, ab);
      ab = __fmaf_rn(rv.y, bv.y, ab);
      ab = __fmaf_rn(rv.z, bv.z, ab);
      ab = __fmaf_rn(rv.w, bv.w, ab);
    }
    float dv = keep ? __fsub_rn(__fadd_rn(a2v, b2p[kk]), __fmul_rn(2.0f, ab))
                    : __builtin_inff();
    int kc2 = kk;
#pragma unroll
    for (int d = 1; d < 64; d <<= 1) {
      float vo = __shfl_xor(dv, d, 64);
      int ko = __shfl_xor(kc2, d, 64);
      if (vo < dv || (vo == dv && ko < kc2)) { dv = vo; kc2 = ko; }
    }
    kw = kc2;
  } else {
    // overflow fallback: exact scan of all k (rare)
    float bd = __builtin_inff(); int bk = 0;
    for (int r = 0; r < KCB / 64; ++r) {
      int kk = r * 64 + lane;
      const float* brow = cbp + (size_t)kk * CDIM;
      float ab = 0.f;
      for (int c4 = 0; c4 < 128; ++c4) {
        float4 rv = ((const float4*)rrow)[c4];
        float4 bv = ((const float4*)brow)[c4];
        ab = __fmaf_rn(rv.x, bv.x, ab);
        ab = __fmaf_rn(rv.y, bv.y, ab);
        ab = __fmaf_rn(rv.z, bv.z, ab);
        ab = __fmaf_rn(rv.w, bv.w, ab);
      }
      float dv = __fsub_rn(__fadd_rn(a2v, b2p[kk]), __fmul_rn(2.0f, ab));
      if (dv < bd || (dv == bd && kk < bk)) { bd = dv; bk = kk; }
    }
#pragma unroll
    for (int d = 1; d < 64; d <<= 1) {
      float vo = __shfl_xor(bd, d, 64);
      int ko = __shfl_xor(bk, d, 64);
      if (vo < bd || (vo == bd && ko < bk)) { bd = vo; bk = ko; }
    }
    kw = bk;
  }
  if (lane == 0) out[IDX_BASE + (size_t)t * NQ + ic] = (float)kw;

  // exact residual update
  const float* qrow = cbp + (size_t)kw * CDIM;
  float* rw = rws + (size_t)t * CDIM;
  int c0 = lane * 8;
  float4 r0 = ((const float4*)(rw + c0))[0];
  float4 r1 = ((const float4*)(rw + c0))[1];
  float4 q0 = ((const float4*)(qrow + c0))[0];
  float4 q1 = ((const float4*)(qrow + c0))[1];
  float4 d0, d1, n0, n1;
  d0.x = __fsub_rn(q0.x, r0.x); d0.y = __fsub_rn(q0.y, r0.y);
  d0.z = __fsub_rn(q0.z, r0.z); d0.w = __fsub_rn(q0.w, r0.w);
  d1.x = __fsub_rn(q1.x, r1.x); d1.y = __fsub_rn(q1.y, r1.y);
  d1.z = __fsub_rn(q1.z, r1.z); d1.w = __fsub_rn(q1.w, r1.w);
  n0.x = __fsub_rn(r0.x, __fadd_rn(r0.x, d0.x));
  n0.y = __fsub_rn(r0.y, __fadd_rn(r0.y, d0.y));
  n0.z = __fsub_rn(r0.z, __fadd_rn(r0.z, d0.z));
  n0.w = __fsub_rn(r0.w, __fadd_rn(r0.w, d0.w));
  n1.x = __fsub_rn(r1.x, __fadd_rn(r1.x, d1.x));
  n1.y = __fsub_rn(r1.y, __fadd_rn(r1.y, d1.y));
  n1.z = __fsub_rn(r1.z, __fadd_rn(r1.z, d1.z));
  n1.w = __fsub_rn(r1.w, __fadd_rn(r1.w, d1.w));
  float lsum = 0.f;
  lsum = __fmaf_rn(d0.x, d0.x, lsum); lsum = __fmaf_rn(d0.y, d0.y, lsum);
  lsum = __fmaf_rn(d0.z, d0.z, lsum); lsum = __fmaf_rn(d0.w, d0.w, lsum);
  lsum = __fmaf_rn(d1.x, d1.x, lsum); lsum = __fmaf_rn(d1.y, d1.y, lsum);
  lsum = __fmaf_rn(d1.z, d1.z, lsum); lsum = __fmaf_rn(d1.w, d1.w, lsum);
  if (ic < 3) {
    ((float4*)(rw + c0))[0] = n0;
    ((float4*)(rw + c0))[1] = n1;
    uint4 u;
    u.x = f2bf(n0.x) | (f2bf(n0.y) << 16);
    u.y = f2bf(n0.z) | (f2bf(n0.w) << 16);
    u.z = f2bf(n1.x) | (f2bf(n1.y) << 16);
    u.w = f2bf(n1.z) | (f2bf(n1.w) << 16);
    *(uint4*)(rbc + (size_t)j * CDIM + c0) = u;
  } else {
    float4 x0 = ((const float4*)(x + (size_t)t * CDIM + c0))[0];
    float4 x1 = ((const float4*)(x + (size_t)t * CDIM + c0))[1];
    float4 o0, o1;
    o0.x = __fsub_rn(x0.x, n0.x); o0.y = __fsub_rn(x0.y, n0.y);
    o0.z = __fsub_rn(x0.z, n0.z); o0.w = __fsub_rn(x0.w, n0.w);
    o1.x = __fsub_rn(x1.x, n1.x); o1.y = __fsub_rn(x1.y, n1.y);
    o1.z = __fsub_rn(x1.z, n1.z); o1.w = __fsub_rn(x1.w, n1.w);
    ((float4*)(rw + c0))[0] = o0;   // rw row == out x_q row
    ((float4*)(rw + c0))[1] = o1;
  }
#pragma unroll
  for (int d = 1; d < 64; d <<= 1) lsum += __shfl_xor(lsum, d, 64);
  if (lane == 0) atomicAdd(lossacc, lsum);
  if (ic < 3 && lane == 0) {
    // exact sequential a2 over the just-written row (same-wave RAW; compiler
    // orders loads after stores via aliasing on rw)
    float s = 0.f;
    for (int c4 = 0; c4 < 128; ++c4) {
      float4 v = ((const float4*)rw)[c4];
      s = __fadd_rn(s, __fmul_rn(v.x, v.x));
      s = __fadd_rn(s, __fmul_rn(v.y, v.y));
      s = __fadd_rn(s, __fmul_rn(v.z, v.z));
      s = __fadd_rn(s, __fmul_rn(v.w, v.w));
    }
    a2c[j] = s;
  }
}

__global__ void k_loss(const int* wsi, const float* acc, float* out) {
  if (threadIdx.x == 0 && blockIdx.x == 0) {
    float n = (float)wsi[2];
    if (n < 1.0f) n = 1.0f;
    out[LOSS_OFF] = acc[0] * 1.25f / (n * (float)CDIM);
  }
}

extern "C" void kernel_launch(void* const* d_in, const int* in_sizes, int n_in,
                              void* d_out, int out_size, void* d_ws, size_t ws_size,
                              hipStream_t stream) {
  const float* x   = (const float*)d_in[0];
  const void* mask = d_in[1];
  const float* cb  = (const float*)d_in[2];
  float* out = (float*)d_out;
  char* ws = (char*)d_ws;
  int*   wsi  = (int*)ws;
  float* wsf  = (float*)ws;
  int*   list = (int*)(ws + WS_LIST);
  float* a2c  = (float*)(ws + WS_A2);
  float* b2   = (float*)(ws + WS_B2);
  unsigned short* rbc = (unsigned short*)(ws + WS_RBC);
  unsigned short* cbb = (unsigned short*)(ws + WS_CBB);
  int*   ccnt = (int*)(ws + WS_CCNT);
  int*   ck   = (int*)(ws + WS_CANDK);
  float* cs   = (float*)(ws + WS_CANDS);
  float* rws  = out;            // x_q region doubles as residual ws (token rows)
  float* b2mx = wsf + 12;

  hipLaunchKernelGGL(k_prep, dim3(1), dim3(1024), 0, stream,
                     (const unsigned char*)mask, wsi, wsf, list);
  hipLaunchKernelGGL(k_fill, dim3(BT / 4), dim3(256), 0, stream, mask, out, wsi);
  hipLaunchKernelGGL(k_b2, dim3(NQ * KCB / 4), dim3(256), 0, stream, cb, b2, b2mx);
  hipLaunchKernelGGL(k_cvtcb, dim3(NQ * KCB * CDIM / 8 / 256), dim3(256), 0, stream, cb, cbb);
  hipLaunchKernelGGL(k_init, dim3(BT / 8), dim3(256), 0, stream,
                     x, rws, rbc, wsi, list, a2c, ccnt);
  for (int ic = 0; ic < NQ; ic++) {
    hipLaunchKernelGGL(k_gemm, dim3((BT / 128) * 8), dim3(256), 0, stream,
                       rbc, cbb, b2, b2mx, a2c, wsi, ccnt, ck, cs, ic);
    hipLaunchKernelGGL(k_pick, dim3(BT / 4), dim3(256), 0, stream,
                       x, cb, rws, rbc, list, wsi, a2c, b2, b2mx, ccnt, ck, cs,
                       out, wsf + 8, ic);
  }
  hipLaunchKernelGGL(k_loss, dim3(1), dim3(1), 0, stream, wsi, wsf + 8, out);
}